// Round 6
// baseline (524.236 us; speedup 1.0000x reference)
//
#include <hip/hip_runtime.h>
#include <math.h>

// MaskedBalancedBCELoss — hard-negative mining via count-histogram select.
//
// R16: de-censored ablation + fix candidate. R15 result: both ab_loads and
// ab_atom ran FASTER than 68us (absent from top-5; sum ~49us from total
// arithmetic) -> loads alone ~25-35us (~5 TB/s), atomics alone ~15us.
// Neither component is the wall; k1 is pinned ~70-75us across VGPR 16/36/52.
// The wall is an INTERACTION. Remaining differences between k1 and the fast
// ablations: data-dependent divergent branch around the atomic, per-element
// f64 accumulate, 3-stream x atomic combination.
// This round: REP-amplified diagnostics (per-rep address shift defeats load
// CSE; per-pass = dur/REP) so they appear in top-5, plus fix-candidate k1b
// (branchless unconditional atomic to per-lane dummy bin, f32 psum) on
// scratch. Real path = R11 k1/k5 verbatim (correctness preserved).

#define NBINS1 4096
#define K1_BLOCKS 1024
#define AREP_L 4
#define AREP_A 8
#define AREP_N 4
#define AREP_B 4

struct Ctrl {
  unsigned long long pos_cnt;
  unsigned long long neg_cnt;
  unsigned long long k;
  double pos_sum;
  unsigned B;
  unsigned k_rem;
};

#define LN2F 0.69314718055994530942f

__device__ __forceinline__ double bin_mid(unsigned b) {
  return (double)__uint_as_float((b << 19) | 0x40000u);
}

// Per-element processing. Loss value bit-identical to R10..R15.
__device__ __forceinline__ void proc1(float p, float g, float m,
                                      unsigned& pc, unsigned& nc,
                                      double& psum, unsigned* __restrict__ hc) {
  bool gpos = (g != 0.0f);
  bool valid = (m != 0.0f);
  bool ispos = valid && gpos;
  bool isneg = valid && !gpos;
  float x = gpos ? p : 1.0f - p;
  float loss = -fmaxf(__log2f(x) * LN2F, -100.0f);
  pc += ispos ? 1u : 0u;
  nc += isneg ? 1u : 0u;
  psum += ispos ? (double)loss : 0.0;
  if (isneg) atomicAdd(&hc[__float_as_uint(loss) >> 19], 1u);
}

// ---------------- Kernel 1: reductions + level-1 histogram -----------------
// R11 verbatim.
extern "C" __global__ void __launch_bounds__(256, 4)
k1_hist(const float* __restrict__ pred, const float* __restrict__ gt,
        const float* __restrict__ mask, unsigned* __restrict__ hist1,
        Ctrl* __restrict__ ctrl, int n4, int n) {
  __shared__ unsigned h[NBINS1];
  for (int i = threadIdx.x; i < NBINS1; i += blockDim.x) h[i] = 0u;
  __syncthreads();

  int wv = threadIdx.x >> 6, ln = threadIdx.x & 63;
  unsigned pc = 0, nc = 0;
  double psum = 0.0;
  const float4* p4 = (const float4*)pred;
  const float4* g4 = (const float4*)gt;
  const float4* m4 = (const float4*)mask;
  int gtid = blockIdx.x * blockDim.x + threadIdx.x;
  int S = gridDim.x * blockDim.x;

  int i = gtid;
  for (; i + 3 * S < n4; i += 4 * S) {
    float4 pv0 = p4[i];
    float4 pv1 = p4[i + S];
    float4 pv2 = p4[i + 2 * S];
    float4 pv3 = p4[i + 3 * S];
    float4 gv0 = g4[i];
    float4 gv1 = g4[i + S];
    float4 gv2 = g4[i + 2 * S];
    float4 gv3 = g4[i + 3 * S];
    float4 mv0 = m4[i];
    float4 mv1 = m4[i + S];
    float4 mv2 = m4[i + 2 * S];
    float4 mv3 = m4[i + 3 * S];
    proc1(pv0.x, gv0.x, mv0.x, pc, nc, psum, h);
    proc1(pv0.y, gv0.y, mv0.y, pc, nc, psum, h);
    proc1(pv0.z, gv0.z, mv0.z, pc, nc, psum, h);
    proc1(pv0.w, gv0.w, mv0.w, pc, nc, psum, h);
    proc1(pv1.x, gv1.x, mv1.x, pc, nc, psum, h);
    proc1(pv1.y, gv1.y, mv1.y, pc, nc, psum, h);
    proc1(pv1.z, gv1.z, mv1.z, pc, nc, psum, h);
    proc1(pv1.w, gv1.w, mv1.w, pc, nc, psum, h);
    proc1(pv2.x, gv2.x, mv2.x, pc, nc, psum, h);
    proc1(pv2.y, gv2.y, mv2.y, pc, nc, psum, h);
    proc1(pv2.z, gv2.z, mv2.z, pc, nc, psum, h);
    proc1(pv2.w, gv2.w, mv2.w, pc, nc, psum, h);
    proc1(pv3.x, gv3.x, mv3.x, pc, nc, psum, h);
    proc1(pv3.y, gv3.y, mv3.y, pc, nc, psum, h);
    proc1(pv3.z, gv3.z, mv3.z, pc, nc, psum, h);
    proc1(pv3.w, gv3.w, mv3.w, pc, nc, psum, h);
  }
  for (; i < n4; i += S) {
    float4 pv = p4[i], gv = g4[i], mv = m4[i];
    proc1(pv.x, gv.x, mv.x, pc, nc, psum, h);
    proc1(pv.y, gv.y, mv.y, pc, nc, psum, h);
    proc1(pv.z, gv.z, mv.z, pc, nc, psum, h);
    proc1(pv.w, gv.w, mv.w, pc, nc, psum, h);
  }
  for (int t = n4 * 4 + gtid; t < n; t += S) {
    proc1(pred[t], gt[t], mask[t], pc, nc, psum, h);
  }

  unsigned long long pcl = pc, ncl = nc;
  for (int off = 32; off > 0; off >>= 1) {
    pcl += __shfl_down(pcl, off);
    ncl += __shfl_down(ncl, off);
    psum += __shfl_down(psum, off);
  }
  __shared__ unsigned long long spc[4], snc[4];
  __shared__ double sps[4];
  if (ln == 0) { spc[wv] = pcl; snc[wv] = ncl; sps[wv] = psum; }
  __syncthreads();
  if (threadIdx.x == 0) {
    unsigned long long tp = 0, tn = 0; double ts = 0.0;
    for (int w = 0; w < 4; w++) { tp += spc[w]; tn += snc[w]; ts += sps[w]; }
    atomicAdd(&ctrl->pos_cnt, tp);
    atomicAdd(&ctrl->neg_cnt, tn);
    unsafeAtomicAdd(&ctrl->pos_sum, ts);
  }
  for (int b = threadIdx.x; b < NBINS1; b += blockDim.x) {
    unsigned c = h[b];
    if (c) atomicAdd(&hist1[b], c);
  }
}

// ---------- Kernel 5: select + midpoint neg_sum + output (1 block) ---------
extern "C" __global__ void __launch_bounds__(256)
k5_final(const unsigned* __restrict__ hist1, Ctrl* __restrict__ ctrl,
         float* __restrict__ out) {
  const int T = 256, CH = NBINS1 / T;
  __shared__ unsigned long long sarr[T];
  __shared__ unsigned long long sk;
  __shared__ unsigned sB, skrem;
  __shared__ double sred[4];
  int t = threadIdx.x;
  int wv = t >> 6, ln = t & 63;

  unsigned cnt[CH];
  unsigned long long tot = 0;
  for (int j = 0; j < CH; j++) { cnt[j] = hist1[t * CH + j]; tot += cnt[j]; }
  sarr[t] = tot;
  if (t == 0) {
    sB = 0xFFFFFFFFu; skrem = 0u;
    unsigned long long pos = ctrl->pos_cnt, negtot = ctrl->neg_cnt;
    unsigned long long k = 0;
    if (pos > 0) {
      k = pos * 3ull;
      if (k > negtot) k = negtot;
    }
    ctrl->k = k;
    sk = k;
  }
  __syncthreads();
  for (int off = 1; off < T; off <<= 1) {
    unsigned long long v = (t + off < T) ? sarr[t + off] : 0ull;
    __syncthreads();
    sarr[t] += v;
    __syncthreads();
  }
  unsigned long long k = sk;
  if (k > 0) {
    unsigned long long above = sarr[t] - tot;
    if (above < k && sarr[t] >= k) {
      unsigned long long cum = above;
      for (int j = CH - 1; j >= 0; j--) {
        if (cum + (unsigned long long)cnt[j] >= k) {
          sB = (unsigned)(t * CH + j);
          skrem = (unsigned)(k - cum);
          break;
        }
        cum += cnt[j];
      }
    }
  }
  __syncthreads();
  unsigned B = sB;

  double s = 0.0;
  if (B != 0xFFFFFFFFu) {
    for (int j = 0; j < CH; j++) {
      unsigned bi = (unsigned)(t * CH + j);
      if (bi > B && cnt[j]) s += (double)cnt[j] * bin_mid(bi);
    }
  }
  for (int off = 32; off > 0; off >>= 1) s += __shfl_down(s, off);
  if (ln == 0) sred[wv] = s;
  __syncthreads();
  if (t == 0) {
    double neg_sum = sred[0] + sred[1] + sred[2] + sred[3];
    if (skrem > 0 && B != 0xFFFFFFFFu)
      neg_sum += (double)skrem * bin_mid(B);
    double denom = (double)ctrl->pos_cnt + (double)k + 1e-6;
    out[0] = (float)((ctrl->pos_sum + neg_sum) / denom);
  }
}

// ------------------- Ablation A: 3-stream loads only (xAREP_L) -------------
extern "C" __global__ void __launch_bounds__(256, 4)
ab_loads(const float* __restrict__ pred, const float* __restrict__ gt,
         const float* __restrict__ mask, float* __restrict__ scratch, int n4) {
  __shared__ unsigned hd[NBINS1];
  for (int i = threadIdx.x; i < NBINS1; i += blockDim.x) hd[i] = 0u;
  __syncthreads();

  const float4* p4 = (const float4*)pred;
  const float4* g4 = (const float4*)gt;
  const float4* m4 = (const float4*)mask;
  int gtid = blockIdx.x * blockDim.x + threadIdx.x;
  int S = gridDim.x * blockDim.x;

  float ax = 0.f, ay = 0.f, az = 0.f, aw = 0.f;
  for (int rep = 0; rep < AREP_L; ++rep) {
    // rep-shifted base defeats cross-rep load CSE; pattern otherwise identical
    for (int i = gtid; i + 3 * S + AREP_L < n4; i += 4 * S) {
      int j = i + rep;
      float4 a0 = p4[j], a1 = p4[j + S], a2 = p4[j + 2 * S], a3 = p4[j + 3 * S];
      float4 b0 = g4[j], b1 = g4[j + S], b2 = g4[j + 2 * S], b3 = g4[j + 3 * S];
      float4 c0 = m4[j], c1 = m4[j + S], c2 = m4[j + 2 * S], c3 = m4[j + 3 * S];
      ax += a0.x + b0.x + c0.x + a1.x + b1.x + c1.x + a2.x + b2.x + c2.x + a3.x + b3.x + c3.x;
      ay += a0.y + b0.y + c0.y + a1.y + b1.y + c1.y + a2.y + b2.y + c2.y + a3.y + b3.y + c3.y;
      az += a0.z + b0.z + c0.z + a1.z + b1.z + c1.z + a2.z + b2.z + c2.z + a3.z + b3.z + c3.z;
      aw += a0.w + b0.w + c0.w + a1.w + b1.w + c1.w + a2.w + b2.w + c2.w + a3.w + b3.w + c3.w;
    }
  }
  float s = ax + ay + az + aw;
  for (int off = 32; off > 0; off >>= 1) s += __shfl_down(s, off);
  s += (float)hd[threadIdx.x & (NBINS1 - 1)];
  if ((threadIdx.x & 63) == 0)
    scratch[blockIdx.x * 4 + (threadIdx.x >> 6)] = s;
}

// -------- Ablation B: pred load + full-rate LDS atomics (xAREP_A) ----------
extern "C" __global__ void __launch_bounds__(256, 4)
ab_atom(const float* __restrict__ pred, unsigned* __restrict__ shist, int n4) {
  __shared__ unsigned h[NBINS1];
  for (int i = threadIdx.x; i < NBINS1; i += blockDim.x) h[i] = 0u;
  __syncthreads();

  const float4* p4 = (const float4*)pred;
  int gtid = blockIdx.x * blockDim.x + threadIdx.x;
  int S = gridDim.x * blockDim.x;

  for (int rep = 0; rep < AREP_A; ++rep) {
    for (int i = gtid; i + 3 * S + AREP_A < n4; i += 4 * S) {
      int jb = i + rep;
      float4 v0 = p4[jb], v1 = p4[jb + S], v2 = p4[jb + 2 * S], v3 = p4[jb + 3 * S];
      float a[16] = {v0.x, v0.y, v0.z, v0.w, v1.x, v1.y, v1.z, v1.w,
                     v2.x, v2.y, v2.z, v2.w, v3.x, v3.y, v3.z, v3.w};
#pragma unroll
      for (int j = 0; j < 16; j++) {
        float loss = -fmaxf(__log2f(1.0f - a[j]) * LN2F, -100.0f);
        atomicAdd(&h[__float_as_uint(loss) >> 19], 1u);
      }
    }
  }
  __syncthreads();
  for (int b = threadIdx.x; b < NBINS1; b += blockDim.x) {
    unsigned c = h[b];
    if (c) atomicAdd(&shist[b], c);
  }
}

// ---- Ablation C: FULL k1 structure minus only the ds_add (xAREP_N) --------
extern "C" __global__ void __launch_bounds__(256, 4)
ab_noatom(const float* __restrict__ pred, const float* __restrict__ gt,
          const float* __restrict__ mask, float* __restrict__ scratch, int n4) {
  __shared__ unsigned hd[NBINS1];
  for (int i = threadIdx.x; i < NBINS1; i += blockDim.x) hd[i] = 0u;
  __syncthreads();

  const float4* p4 = (const float4*)pred;
  const float4* g4 = (const float4*)gt;
  const float4* m4 = (const float4*)mask;
  int gtid = blockIdx.x * blockDim.x + threadIdx.x;
  int S = gridDim.x * blockDim.x;

  unsigned pc = 0, nc = 0, dsum = 0;
  double psum = 0.0;
  for (int rep = 0; rep < AREP_N; ++rep) {
    for (int i = gtid; i + 3 * S + AREP_N < n4; i += 4 * S) {
      int jb = i + rep;
      float4 pv0 = p4[jb], pv1 = p4[jb + S], pv2 = p4[jb + 2 * S], pv3 = p4[jb + 3 * S];
      float4 gv0 = g4[jb], gv1 = g4[jb + S], gv2 = g4[jb + 2 * S], gv3 = g4[jb + 3 * S];
      float4 mv0 = m4[jb], mv1 = m4[jb + S], mv2 = m4[jb + 2 * S], mv3 = m4[jb + 3 * S];
      float pa[16] = {pv0.x, pv0.y, pv0.z, pv0.w, pv1.x, pv1.y, pv1.z, pv1.w,
                      pv2.x, pv2.y, pv2.z, pv2.w, pv3.x, pv3.y, pv3.z, pv3.w};
      float ga[16] = {gv0.x, gv0.y, gv0.z, gv0.w, gv1.x, gv1.y, gv1.z, gv1.w,
                      gv2.x, gv2.y, gv2.z, gv2.w, gv3.x, gv3.y, gv3.z, gv3.w};
      float ma[16] = {mv0.x, mv0.y, mv0.z, mv0.w, mv1.x, mv1.y, mv1.z, mv1.w,
                      mv2.x, mv2.y, mv2.z, mv2.w, mv3.x, mv3.y, mv3.z, mv3.w};
#pragma unroll
      for (int j = 0; j < 16; j++) {
        bool gpos = (ga[j] != 0.0f);
        bool valid = (ma[j] != 0.0f);
        bool ispos = valid && gpos;
        bool isneg = valid && !gpos;
        float x = gpos ? pa[j] : 1.0f - pa[j];
        float loss = -fmaxf(__log2f(x) * LN2F, -100.0f);
        pc += ispos ? 1u : 0u;
        nc += isneg ? 1u : 0u;
        psum += ispos ? (double)loss : 0.0;
        if (isneg) dsum += (__float_as_uint(loss) >> 19);   // consume, no DS op
      }
    }
  }
  float s = (float)psum + (float)pc + (float)nc + (float)dsum;
  for (int off = 32; off > 0; off >>= 1) s += __shfl_down(s, off);
  s += (float)hd[threadIdx.x & (NBINS1 - 1)];
  if ((threadIdx.x & 63) == 0)
    scratch[blockIdx.x * 4 + (threadIdx.x >> 6)] = s;
}

// ---- k1b: FIX CANDIDATE (xAREP_B, on scratch) -----------------------------
// Branchless: unconditional atomic, non-negatives routed to per-lane dummy
// bins >= NBINS1 (conflict-free); psum in f32.
extern "C" __global__ void __launch_bounds__(256, 4)
k1b_cand(const float* __restrict__ pred, const float* __restrict__ gt,
         const float* __restrict__ mask, unsigned* __restrict__ shist,
         float* __restrict__ scratch, int n4) {
  __shared__ unsigned h[NBINS1 + 64];
  for (int i = threadIdx.x; i < NBINS1 + 64; i += blockDim.x) h[i] = 0u;
  __syncthreads();

  const float4* p4 = (const float4*)pred;
  const float4* g4 = (const float4*)gt;
  const float4* m4 = (const float4*)mask;
  int gtid = blockIdx.x * blockDim.x + threadIdx.x;
  int S = gridDim.x * blockDim.x;
  unsigned ln = threadIdx.x & 63;

  unsigned pc = 0, nc = 0;
  float psumf = 0.0f;
  for (int rep = 0; rep < AREP_B; ++rep) {
    for (int i = gtid; i + 3 * S + AREP_B < n4; i += 4 * S) {
      int jb = i + rep;
      float4 pv0 = p4[jb], pv1 = p4[jb + S], pv2 = p4[jb + 2 * S], pv3 = p4[jb + 3 * S];
      float4 gv0 = g4[jb], gv1 = g4[jb + S], gv2 = g4[jb + 2 * S], gv3 = g4[jb + 3 * S];
      float4 mv0 = m4[jb], mv1 = m4[jb + S], mv2 = m4[jb + 2 * S], mv3 = m4[jb + 3 * S];
      float pa[16] = {pv0.x, pv0.y, pv0.z, pv0.w, pv1.x, pv1.y, pv1.z, pv1.w,
                      pv2.x, pv2.y, pv2.z, pv2.w, pv3.x, pv3.y, pv3.z, pv3.w};
      float ga[16] = {gv0.x, gv0.y, gv0.z, gv0.w, gv1.x, gv1.y, gv1.z, gv1.w,
                      gv2.x, gv2.y, gv2.z, gv2.w, gv3.x, gv3.y, gv3.z, gv3.w};
      float ma[16] = {mv0.x, mv0.y, mv0.z, mv0.w, mv1.x, mv1.y, mv1.z, mv1.w,
                      mv2.x, mv2.y, mv2.z, mv2.w, mv3.x, mv3.y, mv3.z, mv3.w};
#pragma unroll
      for (int j = 0; j < 16; j++) {
        bool gpos = (ga[j] != 0.0f);
        bool valid = (ma[j] != 0.0f);
        bool ispos = valid && gpos;
        bool isneg = valid && !gpos;
        float x = gpos ? pa[j] : 1.0f - pa[j];
        float loss = -fmaxf(__log2f(x) * LN2F, -100.0f);
        pc += ispos ? 1u : 0u;
        nc += isneg ? 1u : 0u;
        psumf += ispos ? loss : 0.0f;
        unsigned b = isneg ? (__float_as_uint(loss) >> 19) : (NBINS1 + ln);
        atomicAdd(&h[b], 1u);   // unconditional: no exec-mask branch
      }
    }
  }
  float s = psumf + (float)pc + (float)nc;
  for (int off = 32; off > 0; off >>= 1) s += __shfl_down(s, off);
  if ((threadIdx.x & 63) == 0)
    scratch[1024 * 4 + blockIdx.x * 4 + (threadIdx.x >> 6)] = s;
  __syncthreads();
  for (int b = threadIdx.x; b < NBINS1; b += blockDim.x) {
    unsigned c = h[b];
    if (c) atomicAdd(&shist[b], c);
  }
}

// ---------------------------------------------------------------------------
extern "C" void kernel_launch(void* const* d_in, const int* in_sizes, int n_in,
                              void* d_out, int out_size, void* d_ws, size_t ws_size,
                              hipStream_t stream) {
  const float* pred = (const float*)d_in[0];
  const float* gt   = (const float*)d_in[1];
  const float* mask = (const float*)d_in[2];
  float* out = (float*)d_out;
  int n = in_sizes[0];
  int n4 = n / 4;
  char* ws = (char*)d_ws;

  const size_t HIST1_OFF = 256;
  const size_t ZERO_BYTES = HIST1_OFF + NBINS1 * sizeof(unsigned);   // 16640
  // diagnostics layout (values never read for correctness; no zeroing needed)
  const size_t DG_SCRATCH_OFF = 128 * 1024;   // floats, 64KB
  const size_t DG_HIST_OFF = 192 * 1024;      // unsigned, 32KB
  const size_t DG_END = 256 * 1024;

  Ctrl* ctrl = (Ctrl*)ws;
  unsigned* hist1 = (unsigned*)(ws + HIST1_OFF);

  hipMemsetAsync(d_ws, 0, ZERO_BYTES, stream);
  k1_hist<<<K1_BLOCKS, 256, 0, stream>>>(pred, gt, mask, hist1, ctrl, n4, n);
  k5_final<<<1, 256, 0, stream>>>(hist1, ctrl, out);

  if (ws_size >= DG_END) {
    float* dgs = (float*)(ws + DG_SCRATCH_OFF);
    unsigned* dgh = (unsigned*)(ws + DG_HIST_OFF);
    ab_loads<<<K1_BLOCKS, 256, 0, stream>>>(pred, gt, mask, dgs, n4);
    ab_atom<<<K1_BLOCKS, 256, 0, stream>>>(pred, dgh, n4);
    ab_noatom<<<K1_BLOCKS, 256, 0, stream>>>(pred, gt, mask, dgs, n4);
    k1b_cand<<<K1_BLOCKS, 256, 0, stream>>>(pred, gt, mask, dgh, dgs, n4);
  }
}

// Round 7
// 183.966 us; speedup vs baseline: 2.8496x; 2.8496x over previous
//
#include <hip/hip_runtime.h>
#include <math.h>

// MaskedBalancedBCELoss — hard-negative mining via count-histogram select.
//
// R17: promote the R16-verified branchless-atomic structure to the real k1.
// R16 ablation verdict: the 75us wall was the DIVERGENT BRANCH AROUND THE
// LDS ATOMIC (if(isneg) atomicAdd) — ~85% of lanes took it, and the
// per-element saveexec/branch sequence serialized the load pipeline.
//   - ab_loads  (3-stream loads only)            : ~25us/pass  (roofline)
//   - ab_atom   (full-rate unconditional atomics): <25us/pass
//   - ab_noatom (branches+f64, NO atomic)        : <25us/pass
//   - k1b_cand  (branchless UNCONDITIONAL atomic): 24.7us/pass = 6.35 TB/s
// VGPR count never mattered (k1b at VGPR 32 hits roofline); bank conflicts
// (4.0M) are harmless. Fix: unconditional atomicAdd to
//   b = isneg ? bin : NBINS1+lane   (64 dummy bins, 2-way aliasing = free),
// f32 per-thread psum partial (~2.3 positives/thread, error ~1e-10 rel)
// promoted to f64 at the wave reduce. Flush ignores dummy bins.
// k5 / memset / grid unchanged. Predicted k1 ~25-28us, total ~140us.

#define NBINS1 4096
#define K1_BLOCKS 1024

struct Ctrl {
  unsigned long long pos_cnt;
  unsigned long long neg_cnt;
  unsigned long long k;
  double pos_sum;
  unsigned B;
  unsigned k_rem;
};

#define LN2F 0.69314718055994530942f

__device__ __forceinline__ double bin_mid(unsigned b) {
  return (double)__uint_as_float((b << 19) | 0x40000u);
}

// Per-element processing, branchless-atomic form (R16 k1b_cand, verified
// 24.7us/pass). Loss value bit-identical to R10..R16 (same expression tree)
// -> same bins -> midpoint model unchanged.
__device__ __forceinline__ void proc1(float p, float g, float m, unsigned ln,
                                      unsigned& pc, unsigned& nc,
                                      float& psumf, unsigned* __restrict__ hc) {
  bool gpos = (g != 0.0f);
  bool valid = (m != 0.0f);
  bool ispos = valid && gpos;
  bool isneg = valid && !gpos;
  float x = gpos ? p : 1.0f - p;
  float loss = -fmaxf(__log2f(x) * LN2F, -100.0f);
  pc += ispos ? 1u : 0u;
  nc += isneg ? 1u : 0u;
  psumf += ispos ? loss : 0.0f;
  unsigned b = isneg ? (__float_as_uint(loss) >> 19) : (NBINS1 + ln);
  atomicAdd(&hc[b], 1u);   // unconditional: no exec-mask branch
}

// ---------------- Kernel 1: reductions + level-1 histogram -----------------
extern "C" __global__ void __launch_bounds__(256, 4)
k1_hist(const float* __restrict__ pred, const float* __restrict__ gt,
        const float* __restrict__ mask, unsigned* __restrict__ hist1,
        Ctrl* __restrict__ ctrl, int n4, int n) {
  __shared__ unsigned h[NBINS1 + 64];
  for (int i = threadIdx.x; i < NBINS1 + 64; i += blockDim.x) h[i] = 0u;
  __syncthreads();

  int wv = threadIdx.x >> 6;
  unsigned ln = threadIdx.x & 63;

  unsigned pc = 0, nc = 0;
  float psumf = 0.0f;
  const float4* p4 = (const float4*)pred;
  const float4* g4 = (const float4*)gt;
  const float4* m4 = (const float4*)mask;
  int gtid = blockIdx.x * blockDim.x + threadIdx.x;
  int S = gridDim.x * blockDim.x;

  int i = gtid;
  for (; i + 3 * S < n4; i += 4 * S) {
    float4 pv0 = p4[i];
    float4 pv1 = p4[i + S];
    float4 pv2 = p4[i + 2 * S];
    float4 pv3 = p4[i + 3 * S];
    float4 gv0 = g4[i];
    float4 gv1 = g4[i + S];
    float4 gv2 = g4[i + 2 * S];
    float4 gv3 = g4[i + 3 * S];
    float4 mv0 = m4[i];
    float4 mv1 = m4[i + S];
    float4 mv2 = m4[i + 2 * S];
    float4 mv3 = m4[i + 3 * S];

    proc1(pv0.x, gv0.x, mv0.x, ln, pc, nc, psumf, h);
    proc1(pv0.y, gv0.y, mv0.y, ln, pc, nc, psumf, h);
    proc1(pv0.z, gv0.z, mv0.z, ln, pc, nc, psumf, h);
    proc1(pv0.w, gv0.w, mv0.w, ln, pc, nc, psumf, h);
    proc1(pv1.x, gv1.x, mv1.x, ln, pc, nc, psumf, h);
    proc1(pv1.y, gv1.y, mv1.y, ln, pc, nc, psumf, h);
    proc1(pv1.z, gv1.z, mv1.z, ln, pc, nc, psumf, h);
    proc1(pv1.w, gv1.w, mv1.w, ln, pc, nc, psumf, h);
    proc1(pv2.x, gv2.x, mv2.x, ln, pc, nc, psumf, h);
    proc1(pv2.y, gv2.y, mv2.y, ln, pc, nc, psumf, h);
    proc1(pv2.z, gv2.z, mv2.z, ln, pc, nc, psumf, h);
    proc1(pv2.w, gv2.w, mv2.w, ln, pc, nc, psumf, h);
    proc1(pv3.x, gv3.x, mv3.x, ln, pc, nc, psumf, h);
    proc1(pv3.y, gv3.y, mv3.y, ln, pc, nc, psumf, h);
    proc1(pv3.z, gv3.z, mv3.z, ln, pc, nc, psumf, h);
    proc1(pv3.w, gv3.w, mv3.w, ln, pc, nc, psumf, h);
  }
  // remainder grid-stride steps (branchless too)
  for (; i < n4; i += S) {
    float4 pv = p4[i], gv = g4[i], mv = m4[i];
    proc1(pv.x, gv.x, mv.x, ln, pc, nc, psumf, h);
    proc1(pv.y, gv.y, mv.y, ln, pc, nc, psumf, h);
    proc1(pv.z, gv.z, mv.z, ln, pc, nc, psumf, h);
    proc1(pv.w, gv.w, mv.w, ln, pc, nc, psumf, h);
  }
  // scalar tail (n % 4 != 0)
  for (int t = n4 * 4 + gtid; t < n; t += S) {
    proc1(pred[t], gt[t], mask[t], ln, pc, nc, psumf, h);
  }

  // block reduce pc/nc/psum (psum promoted to f64 here; per-thread f32
  // partial holds only ~2.3 values -> error ~1e-10 relative)
  unsigned long long pcl = pc, ncl = nc;
  double psum = (double)psumf;
  for (int off = 32; off > 0; off >>= 1) {
    pcl += __shfl_down(pcl, off);
    ncl += __shfl_down(ncl, off);
    psum += __shfl_down(psum, off);
  }
  __shared__ unsigned long long spc[4], snc[4];
  __shared__ double sps[4];
  if (ln == 0) { spc[wv] = pcl; snc[wv] = ncl; sps[wv] = psum; }
  __syncthreads();   // also ensures all LDS histogram atomics are complete
  if (threadIdx.x == 0) {
    unsigned long long tp = 0, tn = 0; double ts = 0.0;
    for (int w = 0; w < 4; w++) { tp += spc[w]; tn += snc[w]; ts += sps[w]; }
    atomicAdd(&ctrl->pos_cnt, tp);
    atomicAdd(&ctrl->neg_cnt, tn);
    unsafeAtomicAdd(&ctrl->pos_sum, ts);
  }
  // flush LDS histogram to global (skip empty bins; dummy bins ignored)
  for (int b = threadIdx.x; b < NBINS1; b += blockDim.x) {
    unsigned c = h[b];
    if (c) atomicAdd(&hist1[b], c);
  }
}

// ---------- Kernel 5: select + midpoint neg_sum + output (1 block) ---------
extern "C" __global__ void __launch_bounds__(256)
k5_final(const unsigned* __restrict__ hist1, Ctrl* __restrict__ ctrl,
         float* __restrict__ out) {
  const int T = 256, CH = NBINS1 / T;  // 16 bins per thread
  __shared__ unsigned long long sarr[T];
  __shared__ unsigned long long sk;
  __shared__ unsigned sB, skrem;
  __shared__ double sred[4];
  int t = threadIdx.x;
  int wv = t >> 6, ln = t & 63;

  unsigned cnt[CH];
  unsigned long long tot = 0;
  for (int j = 0; j < CH; j++) { cnt[j] = hist1[t * CH + j]; tot += cnt[j]; }
  sarr[t] = tot;
  if (t == 0) {
    sB = 0xFFFFFFFFu; skrem = 0u;
    unsigned long long pos = ctrl->pos_cnt, negtot = ctrl->neg_cnt;
    unsigned long long k = 0;
    if (pos > 0) {               // FALLBACK_NEG=0 when pos==0
      k = pos * 3ull;            // floor(pos*3.0), exact in integer
      if (k > negtot) k = negtot;
    }
    ctrl->k = k;
    sk = k;
  }
  __syncthreads();
  // inclusive suffix scan: sarr[t] = sum over threads >= t
  for (int off = 1; off < T; off <<= 1) {
    unsigned long long v = (t + off < T) ? sarr[t + off] : 0ull;
    __syncthreads();
    sarr[t] += v;
    __syncthreads();
  }
  unsigned long long k = sk;
  if (k > 0) {
    unsigned long long above = sarr[t] - tot;
    if (above < k && sarr[t] >= k) {
      unsigned long long cum = above;
      for (int j = CH - 1; j >= 0; j--) {
        if (cum + (unsigned long long)cnt[j] >= k) {
          sB = (unsigned)(t * CH + j);
          skrem = (unsigned)(k - cum);
          break;
        }
        cum += cnt[j];
      }
    }
  }
  __syncthreads();
  unsigned B = sB;

  // neg_sum (midpoint model): each thread sums its own bins above B
  double s = 0.0;
  if (B != 0xFFFFFFFFu) {
    for (int j = 0; j < CH; j++) {
      unsigned bi = (unsigned)(t * CH + j);
      if (bi > B && cnt[j]) s += (double)cnt[j] * bin_mid(bi);
    }
  }
  for (int off = 32; off > 0; off >>= 1) s += __shfl_down(s, off);
  if (ln == 0) sred[wv] = s;
  __syncthreads();
  if (t == 0) {
    double neg_sum = sred[0] + sred[1] + sred[2] + sred[3];
    if (skrem > 0 && B != 0xFFFFFFFFu)
      neg_sum += (double)skrem * bin_mid(B);
    double denom = (double)ctrl->pos_cnt + (double)k + 1e-6;
    out[0] = (float)((ctrl->pos_sum + neg_sum) / denom);
  }
}

// ---------------------------------------------------------------------------
extern "C" void kernel_launch(void* const* d_in, const int* in_sizes, int n_in,
                              void* d_out, int out_size, void* d_ws, size_t ws_size,
                              hipStream_t stream) {
  const float* pred = (const float*)d_in[0];
  const float* gt   = (const float*)d_in[1];
  const float* mask = (const float*)d_in[2];
  float* out = (float*)d_out;
  int n = in_sizes[0];
  int n4 = n / 4;
  char* ws = (char*)d_ws;

  // layout: ctrl@0 (64B), hist1@256 (16KB) -> zero first 16640 bytes
  const size_t HIST1_OFF = 256;
  const size_t ZERO_BYTES = HIST1_OFF + NBINS1 * sizeof(unsigned);   // 16640

  Ctrl* ctrl = (Ctrl*)ws;
  unsigned* hist1 = (unsigned*)(ws + HIST1_OFF);

  hipMemsetAsync(d_ws, 0, ZERO_BYTES, stream);
  k1_hist<<<K1_BLOCKS, 256, 0, stream>>>(pred, gt, mask, hist1, ctrl, n4, n);
  k5_final<<<1, 256, 0, stream>>>(hist1, ctrl, out);
}